// Round 7
// baseline (197.731 us; speedup 1.0000x reference)
//
#include <hip/hip_runtime.h>

#define BB 32
#define NN 1024
#define EE 16384
#define NEG 0.2f

// ---------------- float4 helpers ----------------
__device__ __forceinline__ float4 f4(float v) { return make_float4(v, v, v, v); }
__device__ __forceinline__ float4 f4max(float4 a, float4 b) {
    return make_float4(fmaxf(a.x, b.x), fmaxf(a.y, b.y), fmaxf(a.z, b.z), fmaxf(a.w, b.w));
}
__device__ __forceinline__ float4 f4add(float4 a, float4 b) {
    return make_float4(a.x + b.x, a.y + b.y, a.z + b.z, a.w + b.w);
}
__device__ __forceinline__ float4 f4sub(float4 a, float4 b) {
    return make_float4(a.x - b.x, a.y - b.y, a.z - b.z, a.w - b.w);
}
__device__ __forceinline__ float4 f4mul(float4 a, float4 b) {
    return make_float4(a.x * b.x, a.y * b.y, a.z * b.z, a.w * b.w);
}
__device__ __forceinline__ float4 f4exp(float4 a) {
    return make_float4(__expf(a.x), __expf(a.y), __expf(a.z), __expf(a.w));
}
__device__ __forceinline__ float4 shflx4(float4 v, int o) {
    return make_float4(__shfl_xor(v.x, o), __shfl_xor(v.y, o),
                       __shfl_xor(v.z, o), __shfl_xor(v.w, o));
}
__device__ __forceinline__ float4 leaky4(float4 z) {
    return make_float4(z.x > 0.f ? z.x : NEG * z.x, z.y > 0.f ? z.y : NEG * z.y,
                       z.z > 0.f ? z.z : NEG * z.z, z.w > 0.f ? z.w : NEG * z.w);
}

// ======== D1: edge count (blocks 0..127) + weight-fold stage 1 (128..152) ===
__global__ __launch_bounds__(256) void k_count_prep1(
    const int* __restrict__ ei0, const int* __restrict__ ei1,
    int* __restrict__ cnt, const float* __restrict__ W0,
    const float* __restrict__ W1, const float* __restrict__ atts0,
    const float* __restrict__ attd0, const float* __restrict__ atts1,
    const float* __restrict__ attd1, float* __restrict__ ws1g,
    float* __restrict__ wd1g, float* __restrict__ ws0g,
    float* __restrict__ wd0g, float* __restrict__ Ug) {
    int blk = blockIdx.x, t = threadIdx.x;
    if (blk < 128) {
        int list = blk >> 6;
        int e = ((blk & 63) << 8) + t;
        const int* ei = list ? ei1 : ei0;
        atomicAdd(&cnt[(list << 10) + ei[EE + e]], 1);
        return;
    }
    int gid = ((blk - 128) << 8) + t;
    if (gid < 4096) {
        int i = gid >> 8, tt = gid & 255;
        int hp = i >> 2, f = i & 3;
        float a = 0.f;
        for (int c = 0; c < 64; ++c)
            a += W0[f * 256 + hp * 64 + c] * W1[(hp * 64 + c) * 256 + tt];
        Ug[i * 256 + tt] = a;
    } else if (gid < 5120) {
        int q = gid - 4096;
        int tt = q >> 2, h = q & 3;
        float a = 0.f;
        for (int c = 0; c < 64; ++c)
            a += W1[tt * 256 + h * 64 + c] * atts1[h * 64 + c];
        ws1g[q] = a;
    } else if (gid < 6144) {
        int q = gid - 5120;
        int tt = q >> 2, h = q & 3;
        float a = 0.f;
        for (int c = 0; c < 64; ++c)
            a += W1[tt * 256 + h * 64 + c] * attd1[h * 64 + c];
        wd1g[q] = a;
    } else if (gid < 6176) {
        int q = gid - 6144;
        int sel = q >> 4, i = q & 15;
        int f = i >> 2, h = i & 3;
        const float* att = sel ? attd0 : atts0;
        float a = 0.f;
        for (int c = 0; c < 64; ++c)
            a += W0[f * 256 + h * 64 + c] * att[h * 64 + c];
        (sel ? wd0g : ws0g)[i] = a;
    }
}

// ======== D2: scan (blocks 0,1) + prep2 (blocks 2,3) ========
__global__ __launch_bounds__(1024) void k_scan_prep2(
    int* __restrict__ cnt, int* __restrict__ off,
    const float* __restrict__ W0, const float* __restrict__ W1,
    const float* __restrict__ b0, const float* __restrict__ ws1g,
    const float* __restrict__ wd1g, float* __restrict__ Msg,
    float* __restrict__ Mdg, float* __restrict__ csg, float* __restrict__ cdg,
    float* __restrict__ bbw1) {
    int blk = blockIdx.x, t = threadIdx.x;
    if (blk < 2) {
        __shared__ int s[NN];
        int* c = cnt + (blk << 10);
        int* o = off + blk * (NN + 1);
        int v0 = c[t];
        s[t] = v0;
        __syncthreads();
        for (int d = 1; d < NN; d <<= 1) {
            int v = (t >= d) ? s[t - d] : 0;
            __syncthreads();
            s[t] += v;
            __syncthreads();
        }
        int excl = s[t] - v0;
        o[t] = excl;
        c[t] = excl;
        if (t == NN - 1) o[NN] = s[NN - 1];
        return;
    }
    if (blk == 2) {
        if (t < 64) {
            int i = t >> 2, h = t & 3;
            int hp = i >> 2, f = i & 3;
            float a = 0.f;
            for (int c = 0; c < 64; ++c)
                a += W0[f * 256 + hp * 64 + c] * ws1g[(hp * 64 + c) * 4 + h];
            Msg[t] = a;
        } else if (t < 128) {
            int q = t - 64;
            int i = q >> 2, h = q & 3;
            int hp = i >> 2, f = i & 3;
            float a = 0.f;
            for (int c = 0; c < 64; ++c)
                a += W0[f * 256 + hp * 64 + c] * wd1g[(hp * 64 + c) * 4 + h];
            Mdg[q] = a;
        } else if (t < 132) {
            int h = t - 128;
            float a = 0.f;
            for (int tt = 0; tt < 256; ++tt) a += b0[tt] * ws1g[tt * 4 + h];
            csg[h] = a;
        } else if (t < 136) {
            int h = t - 132;
            float a = 0.f;
            for (int tt = 0; tt < 256; ++tt) a += b0[tt] * wd1g[tt * 4 + h];
            cdg[h] = a;
        }
        return;
    }
    if (t < 256) {
        float a = 0.f;
        for (int tp = 0; tp < 256; ++tp) a += b0[tp] * W1[tp * 256 + t];
        bbw1[t] = a;
    }
}

// ======== D3: scatter (blocks 0..127) + prepB (128..168) ========
__global__ __launch_bounds__(256) void k_scat_prepB(
    const int* __restrict__ ei0, const int* __restrict__ ei1,
    int* __restrict__ cur, int* __restrict__ csr,
    const float* __restrict__ W0, const float* __restrict__ fc0w,
    const float* __restrict__ fc0b, const float* __restrict__ b0,
    const float* __restrict__ b1, const float* __restrict__ bbw1,
    const float* __restrict__ Ug, float* __restrict__ Wcat,
    float* __restrict__ c2a, float* __restrict__ c2b) {
    int blk = blockIdx.x, t = threadIdx.x;
    if (blk < 128) {
        int list = blk >> 6;
        int e = ((blk & 63) << 8) + t;
        const int* ei = list ? ei1 : ei0;
        int sv = ei[e];
        int d = ei[EE + e];
        int p = atomicAdd(&cur[(list << 10) + d], 1);
        csr[(list << 14) + p] = sv;
        return;
    }
    int gid = ((blk - 128) << 8) + t;
    if (gid < 8192) {
        int row = gid >> 7, u = gid & 127;
        int h = row >> 4, j = row & 15;
        float a = 0.f;
        for (int c = 0; c < 64; ++c)
            a += Ug[j * 256 + h * 64 + c] * fc0w[(h * 64 + c) * 128 + u];
        Wcat[row * 128 + u] = a;
    } else if (gid < 10240) {
        int row = gid >> 7, u = gid & 127;
        int j = row - 64;
        int h = j >> 2, f = j & 3;
        float a = 0.f;
        for (int c = 0; c < 64; ++c)
            a += W0[f * 256 + h * 64 + c] * fc0w[(h * 64 + c) * 128 + u];
        Wcat[row * 128 + u] = a;
    } else if (gid < 10368) {
        int u = gid - 10240;
        float a = fc0b[u];
        for (int tt = 0; tt < 256; ++tt)
            a += (b1[tt] + b0[tt]) * fc0w[tt * 128 + u];
        c2a[u] = a;
    } else if (gid < 10496) {
        int u = gid - 10368;
        float a = 0.f;
        for (int tt = 0; tt < 256; ++tt) a += bbw1[tt] * fc0w[tt * 128 + u];
        c2b[u] = a;
    }
}

// ======== D4: agg0 — 16-lane group per node, inline as0, fused as1/ad1 ======
__global__ __launch_bounds__(256) void k_agg0(
    const float* __restrict__ x, const int* __restrict__ off,
    const int* __restrict__ csr, const float* __restrict__ ws0g,
    const float* __restrict__ wd0g, const float* __restrict__ Msg,
    const float* __restrict__ Mdg, const float* __restrict__ csg,
    const float* __restrict__ cdg, float* __restrict__ xbar,
    float* __restrict__ as1, float* __restrict__ ad1) {
    int t = threadIdx.x;
    int g = t >> 4, l = t & 15;
    int bn = (blockIdx.x << 4) + g;
    int b = bn >> 10, n = bn & (NN - 1);
    int beg = off[n], end = off[n + 1];
    float ws[16], wd[16];
#pragma unroll
    for (int i = 0; i < 16; ++i) {
        ws[i] = ws0g[i];
        wd[i] = wd0g[i];
    }
    // adv = x[dst] . wd0
    float4 xd = *(const float4*)&x[bn << 2];
    float4 adv;
    adv.x = xd.x * wd[0] + xd.y * wd[4] + xd.z * wd[8] + xd.w * wd[12];
    adv.y = xd.x * wd[1] + xd.y * wd[5] + xd.z * wd[9] + xd.w * wd[13];
    adv.z = xd.x * wd[2] + xd.y * wd[6] + xd.z * wd[10] + xd.w * wd[14];
    adv.w = xd.x * wd[3] + xd.y * wd[7] + xd.z * wd[11] + xd.w * wd[15];
    float4 m4 = f4(-1e30f), den = f4(0.f);
    float pacc[16];
#pragma unroll
    for (int i = 0; i < 16; ++i) pacc[i] = 0.f;
    for (int base = beg + l; base < end; base += 16) {
        int s = csr[base];
        float4 xs = *(const float4*)&x[((b << 10) + s) << 2];
        float4 av;
        av.x = xs.x * ws[0] + xs.y * ws[4] + xs.z * ws[8] + xs.w * ws[12];
        av.y = xs.x * ws[1] + xs.y * ws[5] + xs.z * ws[9] + xs.w * ws[13];
        av.z = xs.x * ws[2] + xs.y * ws[6] + xs.z * ws[10] + xs.w * ws[14];
        av.w = xs.x * ws[3] + xs.y * ws[7] + xs.z * ws[11] + xs.w * ws[15];
        float4 lv = leaky4(f4add(av, adv));
        float4 nm = f4max(m4, lv);
        float4 r = f4exp(f4sub(m4, nm));
        float4 ex = f4exp(f4sub(lv, nm));
        m4 = nm;
        den = f4add(f4mul(den, r), ex);
        float rr[4] = {r.x, r.y, r.z, r.w};
        float exa[4] = {ex.x, ex.y, ex.z, ex.w};
        float xsa[4] = {xs.x, xs.y, xs.z, xs.w};
#pragma unroll
        for (int i = 0; i < 16; ++i)
            pacc[i] = pacc[i] * rr[i >> 2] + exa[i >> 2] * xsa[i & 3];
    }
    float4 ml = m4;
#pragma unroll
    for (int o = 8; o; o >>= 1) m4 = f4max(m4, shflx4(m4, o));
    float4 sc = f4exp(f4sub(ml, m4));
    den = f4mul(den, sc);
    float sca[4] = {sc.x, sc.y, sc.z, sc.w};
#pragma unroll
    for (int i = 0; i < 16; ++i) pacc[i] *= sca[i >> 2];
#pragma unroll
    for (int o = 8; o; o >>= 1) {
        den = f4add(den, shflx4(den, o));
#pragma unroll
        for (int i = 0; i < 16; ++i) pacc[i] += __shfl_xor(pacc[i], o);
    }
    float iva[4] = {1.f / (den.x + 1e-16f), 1.f / (den.y + 1e-16f),
                    1.f / (den.z + 1e-16f), 1.f / (den.w + 1e-16f)};
    float xbn[16];
#pragma unroll
    for (int i = 0; i < 16; ++i) xbn[i] = pacc[i] * iva[i >> 2];
    if (l == 0) {
#pragma unroll
        for (int q = 0; q < 4; ++q) {
            float4 v = make_float4(xbn[q * 4], xbn[q * 4 + 1], xbn[q * 4 + 2],
                                   xbn[q * 4 + 3]);
            *(float4*)&xbar[(bn << 4) + (q << 2)] = v;
        }
    }
    if (l < 8) {
        int h = l & 3, sel = l >> 2;
        const float* M = sel ? Mdg : Msg;
        float a = sel ? cdg[h] : csg[h];
#pragma unroll
        for (int i = 0; i < 16; ++i) a += xbn[i] * M[i * 4 + h];
        (sel ? ad1 : as1)[(bn << 2) + h] = a;
    }
}

// ======== D5: agg1 + final fused — 512 thr = 8 waves = 8 nodes ========
__global__ __launch_bounds__(512) void k_agg1_final(
    const float* __restrict__ xbar, const float* __restrict__ as1,
    const float* __restrict__ ad1, const int* __restrict__ off,
    const int* __restrict__ csr, const float* __restrict__ Wcat,
    const float* __restrict__ c2a, const float* __restrict__ c2b,
    const float* __restrict__ fc1w, const float* __restrict__ fc1b,
    float* __restrict__ out) {
    __shared__ float Ws[80 * 128];
    __shared__ float As[8][88];
    __shared__ float c2as[128], c2bs[128], f1s[128];
    __shared__ int degs[8];
    int t = threadIdx.x;
    for (int i = t; i < 2560; i += 512)
        *(float4*)&Ws[i << 2] = *(const float4*)&Wcat[i << 2];
    if (t < 128) {
        c2as[t] = c2a[t];
        c2bs[t] = c2b[t];
        f1s[t] = fc1w[t];
    }
    int wid = t >> 6, tw = t & 63;
    int h = tw >> 4, slot = tw & 15;
    int bn = (blockIdx.x << 3) + wid;
    int b = bn >> 10, n = bn & (NN - 1);
    int beg = off[n], end = off[n + 1];
    if (tw == 0) degs[wid] = end - beg;
    float adh = ad1[(bn << 2) + h];
    float ml = -1e30f, den = 0.f;
    float pacc[16];
#pragma unroll
    for (int i = 0; i < 16; ++i) pacc[i] = 0.f;
    const float* xbb = xbar + ((size_t)b << 14);
    for (int base = beg + slot; base < end; base += 16) {
        int s = csr[base];
        float av = as1[(((b << 10) + s) << 2) + h];
        float z = av + adh;
        float lv = z > 0.f ? z : NEG * z;
        float nm = fmaxf(ml, lv);
        float r = __expf(ml - nm);
        float ex = __expf(lv - nm);
        ml = nm;
        den = den * r + ex;
        const float* xp = xbb + (s << 4);
        float4 x0 = *(const float4*)(xp);
        float4 x1 = *(const float4*)(xp + 4);
        float4 x2 = *(const float4*)(xp + 8);
        float4 x3 = *(const float4*)(xp + 12);
        float xsa[16] = {x0.x, x0.y, x0.z, x0.w, x1.x, x1.y, x1.z, x1.w,
                         x2.x, x2.y, x2.z, x2.w, x3.x, x3.y, x3.z, x3.w};
#pragma unroll
        for (int i = 0; i < 16; ++i) pacc[i] = pacc[i] * r + ex * xsa[i];
    }
    float M = ml;
#pragma unroll
    for (int o = 8; o; o >>= 1) M = fmaxf(M, __shfl_xor(M, o));
    float sc = __expf(ml - M);
    den *= sc;
#pragma unroll
    for (int i = 0; i < 16; ++i) pacc[i] *= sc;
#pragma unroll
    for (int o = 8; o; o >>= 1) {
        den += __shfl_xor(den, o);
#pragma unroll
        for (int i = 0; i < 16; ++i) pacc[i] += __shfl_xor(pacc[i], o);
    }
    float inv = 1.f / (den + 1e-16f);
    if (slot == 0) {
#pragma unroll
        for (int q = 0; q < 4; ++q) {
            float4 v = make_float4(pacc[q * 4] * inv, pacc[q * 4 + 1] * inv,
                                   pacc[q * 4 + 2] * inv, pacc[q * 4 + 3] * inv);
            *(float4*)&As[wid][(h << 4) + (q << 2)] = v;
        }
    }
    if (tw < 4) {
        float4 v = *(const float4*)&xbar[(bn << 4) + (tw << 2)];
        *(float4*)&As[wid][64 + (tw << 2)] = v;
    }
    __syncthreads();
    int hasdeg = degs[wid] > 0;
    float z0 = c2as[tw] + (hasdeg ? c2bs[tw] : 0.f);
    float z1 = c2as[tw + 64] + (hasdeg ? c2bs[tw + 64] : 0.f);
#pragma unroll 8
    for (int k = 0; k < 80; ++k) {
        float a = As[wid][k];
        z0 += a * Ws[(k << 7) + tw];
        z1 += a * Ws[(k << 7) + tw + 64];
    }
    z0 = z0 > 0.f ? z0 : 0.f;
    z1 = z1 > 0.f ? z1 : 0.f;
    float part = z0 * f1s[tw] + z1 * f1s[tw + 64];
#pragma unroll
    for (int o = 32; o; o >>= 1) part += __shfl_xor(part, o);
    if (tw == 0) out[bn] = part + fc1b[0];
}

// ---------------- launch ----------------
extern "C" void kernel_launch(void* const* d_in, const int* in_sizes, int n_in,
                              void* d_out, int out_size, void* d_ws, size_t ws_size,
                              hipStream_t stream) {
    const float* x = (const float*)d_in[0];
    const int* ei0 = (const int*)d_in[2];
    const int* ei1 = (const int*)d_in[3];
    const float* W0 = (const float*)d_in[4];
    const float* atts0 = (const float*)d_in[5];
    const float* attd0 = (const float*)d_in[6];
    const float* b0 = (const float*)d_in[7];
    const float* W1 = (const float*)d_in[8];
    const float* atts1 = (const float*)d_in[9];
    const float* attd1 = (const float*)d_in[10];
    const float* b1 = (const float*)d_in[11];
    const float* fc0w = (const float*)d_in[12];
    const float* fc0b = (const float*)d_in[13];
    const float* fc1w = (const float*)d_in[14];
    const float* fc1b = (const float*)d_in[15];
    float* out = (float*)d_out;

    float* fw = (float*)d_ws;
    float* xbar = fw;                 fw += (size_t)BB * NN * 16;
    float* as1 = fw;                  fw += (size_t)BB * NN * 4;
    float* ad1 = fw;                  fw += (size_t)BB * NN * 4;
    float* Ug = fw;                   fw += 4096;
    float* Wcat = fw;                 fw += 80 * 128;
    float* bbw1 = fw;                 fw += 256;
    float* c2a = fw;                  fw += 128;
    float* c2b = fw;                  fw += 128;
    float* ws0g = fw;                 fw += 16;
    float* wd0g = fw;                 fw += 16;
    float* Msg = fw;                  fw += 64;
    float* Mdg = fw;                  fw += 64;
    float* csg = fw;                  fw += 4;
    float* cdg = fw;                  fw += 4;
    float* ws1g = fw;                 fw += 1024;
    float* wd1g = fw;                 fw += 1024;
    int* ip = (int*)fw;
    int* off = ip;                    ip += 2 * (NN + 1);
    int* cnt = ip;                    ip += 2 * NN;
    int* csr = ip;

    hipMemsetAsync(cnt, 0, 2 * NN * sizeof(int), stream);
    k_count_prep1<<<153, 256, 0, stream>>>(ei0, ei1, cnt, W0, W1, atts0, attd0,
                                           atts1, attd1, ws1g, wd1g, ws0g,
                                           wd0g, Ug);
    k_scan_prep2<<<4, 1024, 0, stream>>>(cnt, off, W0, W1, b0, ws1g, wd1g,
                                         Msg, Mdg, csg, cdg, bbw1);
    k_scat_prepB<<<169, 256, 0, stream>>>(ei0, ei1, cnt, csr, W0, fc0w, fc0b,
                                          b0, b1, bbw1, Ug, Wcat, c2a, c2b);
    k_agg0<<<BB * NN / 16, 256, 0, stream>>>(x, off, csr, ws0g, wd0g, Msg, Mdg,
                                             csg, cdg, xbar, as1, ad1);
    k_agg1_final<<<BB * NN / 8, 512, 0, stream>>>(
        xbar, as1, ad1, off + (NN + 1), csr + EE, Wcat, c2a, c2b, fc1w, fc1b,
        out);
}

// Round 8
// 182.131 us; speedup vs baseline: 1.0857x; 1.0857x over previous
//
#include <hip/hip_runtime.h>

#define BB 32
#define NN 1024
#define EE 16384
#define NEG 0.2f

// ---------------- float4 helpers ----------------
__device__ __forceinline__ float4 f4(float v) { return make_float4(v, v, v, v); }
__device__ __forceinline__ float4 f4max(float4 a, float4 b) {
    return make_float4(fmaxf(a.x, b.x), fmaxf(a.y, b.y), fmaxf(a.z, b.z), fmaxf(a.w, b.w));
}
__device__ __forceinline__ float4 f4add(float4 a, float4 b) {
    return make_float4(a.x + b.x, a.y + b.y, a.z + b.z, a.w + b.w);
}
__device__ __forceinline__ float4 f4sub(float4 a, float4 b) {
    return make_float4(a.x - b.x, a.y - b.y, a.z - b.z, a.w - b.w);
}
__device__ __forceinline__ float4 f4mul(float4 a, float4 b) {
    return make_float4(a.x * b.x, a.y * b.y, a.z * b.z, a.w * b.w);
}
__device__ __forceinline__ float4 f4exp(float4 a) {
    return make_float4(__expf(a.x), __expf(a.y), __expf(a.z), __expf(a.w));
}
__device__ __forceinline__ float4 shflx4(float4 v, int o) {
    return make_float4(__shfl_xor(v.x, o), __shfl_xor(v.y, o),
                       __shfl_xor(v.z, o), __shfl_xor(v.w, o));
}
__device__ __forceinline__ float4 leaky4(float4 z) {
    return make_float4(z.x > 0.f ? z.x : NEG * z.x, z.y > 0.f ? z.y : NEG * z.y,
                       z.z > 0.f ? z.z : NEG * z.z, z.w > 0.f ? z.w : NEG * z.w);
}

// ======== D1: CSR build fully in-LDS (blocks 0,1) + prep1 (blocks 2..8) ====
__global__ __launch_bounds__(1024) void k_csr_prep1(
    const int* __restrict__ ei0, const int* __restrict__ ei1,
    int* __restrict__ csr, int* __restrict__ off,
    const float* __restrict__ W0, const float* __restrict__ W1,
    const float* __restrict__ atts0, const float* __restrict__ attd0,
    const float* __restrict__ atts1, const float* __restrict__ attd1,
    float* __restrict__ ws1g, float* __restrict__ wd1g,
    float* __restrict__ ws0g, float* __restrict__ wd0g,
    float* __restrict__ Ug) {
    int blk = blockIdx.x, t = threadIdx.x;
    if (blk < 2) {
        __shared__ int cntS[NN];
        __shared__ int tmpS[NN];
        const int* ei = blk ? ei1 : ei0;
        int* o = off + blk * (NN + 1);
        int* c = csr + (blk << 14);
        cntS[t] = 0;
        __syncthreads();
        for (int e = t; e < EE; e += 1024) atomicAdd(&cntS[ei[EE + e]], 1);
        __syncthreads();
        int v0 = cntS[t];
        tmpS[t] = v0;
        __syncthreads();
        for (int d = 1; d < NN; d <<= 1) {
            int v = (t >= d) ? tmpS[t - d] : 0;
            __syncthreads();
            tmpS[t] += v;
            __syncthreads();
        }
        int excl = tmpS[t] - v0;
        o[t] = excl;
        if (t == NN - 1) o[NN] = tmpS[t];
        cntS[t] = excl;   // cursor
        __syncthreads();
        for (int e = t; e < EE; e += 1024) {
            int d = ei[EE + e];
            int p = atomicAdd(&cntS[d], 1);
            c[p] = ei[e];
        }
        return;
    }
    int gid = ((blk - 2) << 10) + t;
    if (gid < 4096) {
        int i = gid >> 8, tt = gid & 255;
        int hp = i >> 2, f = i & 3;
        float a = 0.f;
        for (int c = 0; c < 64; ++c)
            a += W0[f * 256 + hp * 64 + c] * W1[(hp * 64 + c) * 256 + tt];
        Ug[i * 256 + tt] = a;
    } else if (gid < 5120) {
        int q = gid - 4096;
        int tt = q >> 2, h = q & 3;
        float a = 0.f;
        for (int c = 0; c < 64; ++c)
            a += W1[tt * 256 + h * 64 + c] * atts1[h * 64 + c];
        ws1g[q] = a;
    } else if (gid < 6144) {
        int q = gid - 5120;
        int tt = q >> 2, h = q & 3;
        float a = 0.f;
        for (int c = 0; c < 64; ++c)
            a += W1[tt * 256 + h * 64 + c] * attd1[h * 64 + c];
        wd1g[q] = a;
    } else if (gid < 6176) {
        int q = gid - 6144;
        int sel = q >> 4, i = q & 15;
        int f = i >> 2, h = i & 3;
        const float* att = sel ? attd0 : atts0;
        float a = 0.f;
        for (int c = 0; c < 64; ++c)
            a += W0[f * 256 + h * 64 + c] * att[h * 64 + c];
        (sel ? wd0g : ws0g)[i] = a;
    }
}

// ======== D2: prep2 (1 block, 512 thr) ========
__global__ __launch_bounds__(512) void k_prep2(
    const float* __restrict__ W0, const float* __restrict__ W1,
    const float* __restrict__ b0, const float* __restrict__ ws1g,
    const float* __restrict__ wd1g, float* __restrict__ Msg,
    float* __restrict__ Mdg, float* __restrict__ csg, float* __restrict__ cdg,
    float* __restrict__ bbw1) {
    int t = threadIdx.x;
    if (t < 64) {
        int i = t >> 2, h = t & 3;
        int hp = i >> 2, f = i & 3;
        float a = 0.f;
        for (int c = 0; c < 64; ++c)
            a += W0[f * 256 + hp * 64 + c] * ws1g[(hp * 64 + c) * 4 + h];
        Msg[t] = a;
    } else if (t < 128) {
        int q = t - 64;
        int i = q >> 2, h = q & 3;
        int hp = i >> 2, f = i & 3;
        float a = 0.f;
        for (int c = 0; c < 64; ++c)
            a += W0[f * 256 + hp * 64 + c] * wd1g[(hp * 64 + c) * 4 + h];
        Mdg[q] = a;
    } else if (t < 132) {
        int h = t - 128;
        float a = 0.f;
        for (int tt = 0; tt < 256; ++tt) a += b0[tt] * ws1g[tt * 4 + h];
        csg[h] = a;
    } else if (t < 136) {
        int h = t - 132;
        float a = 0.f;
        for (int tt = 0; tt < 256; ++tt) a += b0[tt] * wd1g[tt * 4 + h];
        cdg[h] = a;
    } else if (t >= 256) {
        int tt = t - 256;
        float a = 0.f;
        for (int tp = 0; tp < 256; ++tp) a += b0[tp] * W1[tp * 256 + tt];
        bbw1[tt] = a;
    }
}

// ======== D3: agg0 (blocks 0..2047) + prepB (2048..2088) ========
__global__ __launch_bounds__(256) void k_agg0_prepB(
    const float* __restrict__ x, const int* __restrict__ off,
    const int* __restrict__ csr, const float* __restrict__ ws0g,
    const float* __restrict__ wd0g, const float* __restrict__ Msg,
    const float* __restrict__ Mdg, const float* __restrict__ csg,
    const float* __restrict__ cdg, float* __restrict__ xbar,
    float* __restrict__ as1, float* __restrict__ ad1,
    const float* __restrict__ W0, const float* __restrict__ fc0w,
    const float* __restrict__ fc0b, const float* __restrict__ b0,
    const float* __restrict__ b1, const float* __restrict__ bbw1,
    const float* __restrict__ Ug, float* __restrict__ Wcat,
    float* __restrict__ c2a, float* __restrict__ c2b) {
    int blk = blockIdx.x, t = threadIdx.x;
    if (blk >= 2048) {
        int gid = ((blk - 2048) << 8) + t;
        if (gid < 8192) {
            int row = gid >> 7, u = gid & 127;
            int h = row >> 4, j = row & 15;
            float a = 0.f;
            for (int c = 0; c < 64; ++c)
                a += Ug[j * 256 + h * 64 + c] * fc0w[(h * 64 + c) * 128 + u];
            Wcat[row * 128 + u] = a;
        } else if (gid < 10240) {
            int row = gid >> 7, u = gid & 127;
            int j = row - 64;
            int h = j >> 2, f = j & 3;
            float a = 0.f;
            for (int c = 0; c < 64; ++c)
                a += W0[f * 256 + h * 64 + c] * fc0w[(h * 64 + c) * 128 + u];
            Wcat[row * 128 + u] = a;
        } else if (gid < 10368) {
            int u = gid - 10240;
            float a = fc0b[u];
            for (int tt = 0; tt < 256; ++tt)
                a += (b1[tt] + b0[tt]) * fc0w[tt * 128 + u];
            c2a[u] = a;
        } else if (gid < 10496) {
            int u = gid - 10368;
            float a = 0.f;
            for (int tt = 0; tt < 256; ++tt) a += bbw1[tt] * fc0w[tt * 128 + u];
            c2b[u] = a;
        }
        return;
    }
    int g = t >> 4, l = t & 15;
    int bn = (blk << 4) + g;
    int b = bn >> 10, n = bn & (NN - 1);
    int beg = off[n], end = off[n + 1];
    float ws[16], wd[16];
#pragma unroll
    for (int i = 0; i < 16; ++i) {
        ws[i] = ws0g[i];
        wd[i] = wd0g[i];
    }
    float4 xd = *(const float4*)&x[bn << 2];
    float4 adv;
    adv.x = xd.x * wd[0] + xd.y * wd[4] + xd.z * wd[8] + xd.w * wd[12];
    adv.y = xd.x * wd[1] + xd.y * wd[5] + xd.z * wd[9] + xd.w * wd[13];
    adv.z = xd.x * wd[2] + xd.y * wd[6] + xd.z * wd[10] + xd.w * wd[14];
    adv.w = xd.x * wd[3] + xd.y * wd[7] + xd.z * wd[11] + xd.w * wd[15];
    float4 m4 = f4(-1e30f), den = f4(0.f);
    float pacc[16];
#pragma unroll
    for (int i = 0; i < 16; ++i) pacc[i] = 0.f;
    for (int base = beg + l; base < end; base += 16) {
        int s = csr[base];
        float4 xs = *(const float4*)&x[((b << 10) + s) << 2];
        float4 av;
        av.x = xs.x * ws[0] + xs.y * ws[4] + xs.z * ws[8] + xs.w * ws[12];
        av.y = xs.x * ws[1] + xs.y * ws[5] + xs.z * ws[9] + xs.w * ws[13];
        av.z = xs.x * ws[2] + xs.y * ws[6] + xs.z * ws[10] + xs.w * ws[14];
        av.w = xs.x * ws[3] + xs.y * ws[7] + xs.z * ws[11] + xs.w * ws[15];
        float4 lv = leaky4(f4add(av, adv));
        float4 nm = f4max(m4, lv);
        float4 r = f4exp(f4sub(m4, nm));
        float4 ex = f4exp(f4sub(lv, nm));
        m4 = nm;
        den = f4add(f4mul(den, r), ex);
        float rr[4] = {r.x, r.y, r.z, r.w};
        float exa[4] = {ex.x, ex.y, ex.z, ex.w};
        float xsa[4] = {xs.x, xs.y, xs.z, xs.w};
#pragma unroll
        for (int i = 0; i < 16; ++i)
            pacc[i] = pacc[i] * rr[i >> 2] + exa[i >> 2] * xsa[i & 3];
    }
    float4 ml = m4;
#pragma unroll
    for (int o = 8; o; o >>= 1) m4 = f4max(m4, shflx4(m4, o));
    float4 sc = f4exp(f4sub(ml, m4));
    den = f4mul(den, sc);
    float sca[4] = {sc.x, sc.y, sc.z, sc.w};
#pragma unroll
    for (int i = 0; i < 16; ++i) pacc[i] *= sca[i >> 2];
#pragma unroll
    for (int o = 8; o; o >>= 1) {
        den = f4add(den, shflx4(den, o));
#pragma unroll
        for (int i = 0; i < 16; ++i) pacc[i] += __shfl_xor(pacc[i], o);
    }
    float iva[4] = {1.f / (den.x + 1e-16f), 1.f / (den.y + 1e-16f),
                    1.f / (den.z + 1e-16f), 1.f / (den.w + 1e-16f)};
    float xbn[16];
#pragma unroll
    for (int i = 0; i < 16; ++i) xbn[i] = pacc[i] * iva[i >> 2];
    if (l == 0) {
#pragma unroll
        for (int q = 0; q < 4; ++q) {
            float4 v = make_float4(xbn[q * 4], xbn[q * 4 + 1], xbn[q * 4 + 2],
                                   xbn[q * 4 + 3]);
            *(float4*)&xbar[(bn << 4) + (q << 2)] = v;
        }
    }
    if (l < 8) {
        int h = l & 3, sel = l >> 2;
        const float* M = sel ? Mdg : Msg;
        float a = sel ? cdg[h] : csg[h];
#pragma unroll
        for (int i = 0; i < 16; ++i) a += xbn[i] * M[i * 4 + h];
        (sel ? ad1 : as1)[(bn << 2) + h] = a;
    }
}

// ======== D4: agg1 — 16-lane group per node, all 4 heads per lane ========
__global__ __launch_bounds__(256) void k_agg1(
    const float* __restrict__ xbar, const float* __restrict__ as1,
    const float* __restrict__ ad1, const int* __restrict__ off,
    const int* __restrict__ csr, float* __restrict__ xb2) {
    int t = threadIdx.x;
    int g = t >> 4, l = t & 15;
    int bn = (blockIdx.x << 4) + g;
    int b = bn >> 10, n = bn & (NN - 1);
    int beg = off[n], end = off[n + 1];
    float4 adv = *(const float4*)&ad1[bn << 2];
    float4 m4 = f4(-1e30f), den = f4(0.f);
    float pacc[64];
#pragma unroll
    for (int i = 0; i < 64; ++i) pacc[i] = 0.f;
    const float* xbb = xbar + ((size_t)b << 14);
    for (int base = beg + l; base < end; base += 16) {
        int s = csr[base];
        float4 av = *(const float4*)&as1[(((b << 10) + s)) << 2];
        float4 lv = leaky4(f4add(av, adv));
        float4 nm = f4max(m4, lv);
        float4 r = f4exp(f4sub(m4, nm));
        float4 ex = f4exp(f4sub(lv, nm));
        m4 = nm;
        den = f4add(f4mul(den, r), ex);
        const float* xp = xbb + (s << 4);
        float4 x0 = *(const float4*)(xp);
        float4 x1 = *(const float4*)(xp + 4);
        float4 x2 = *(const float4*)(xp + 8);
        float4 x3 = *(const float4*)(xp + 12);
        float rr[4] = {r.x, r.y, r.z, r.w};
        float exa[4] = {ex.x, ex.y, ex.z, ex.w};
        float xsa[16] = {x0.x, x0.y, x0.z, x0.w, x1.x, x1.y, x1.z, x1.w,
                         x2.x, x2.y, x2.z, x2.w, x3.x, x3.y, x3.z, x3.w};
#pragma unroll
        for (int h = 0; h < 4; ++h)
#pragma unroll
            for (int f = 0; f < 16; ++f)
                pacc[h * 16 + f] = pacc[h * 16 + f] * rr[h] + exa[h] * xsa[f];
    }
    float4 ml = m4;
#pragma unroll
    for (int o = 8; o; o >>= 1) m4 = f4max(m4, shflx4(m4, o));
    float4 sc = f4exp(f4sub(ml, m4));
    den = f4mul(den, sc);
    float sca[4] = {sc.x, sc.y, sc.z, sc.w};
#pragma unroll
    for (int i = 0; i < 64; ++i) pacc[i] *= sca[i >> 4];
#pragma unroll
    for (int o = 8; o; o >>= 1) {
        den = f4add(den, shflx4(den, o));
#pragma unroll
        for (int i = 0; i < 64; ++i) pacc[i] += __shfl_xor(pacc[i], o);
    }
    if (l == 0) {
        float iva[4] = {1.f / (den.x + 1e-16f), 1.f / (den.y + 1e-16f),
                        1.f / (den.z + 1e-16f), 1.f / (den.w + 1e-16f)};
#pragma unroll
        for (int q = 0; q < 16; ++q) {
            float iv = iva[q >> 2];
            float4 v = make_float4(pacc[q * 4] * iv, pacc[q * 4 + 1] * iv,
                                   pacc[q * 4 + 2] * iv, pacc[q * 4 + 3] * iv);
            *(float4*)&xb2[(bn << 6) + (q << 2)] = v;
        }
    }
}

// ======== D5: final GEMM + ReLU + 128-dot (128 nodes/block) ========
#define AP 132
__global__ __launch_bounds__(256) void k_final(
    const float* __restrict__ xbar, const float* __restrict__ xb2,
    const float* __restrict__ Wcat, const float* __restrict__ c2a,
    const float* __restrict__ c2b, const float* __restrict__ fc1w,
    const float* __restrict__ fc1b, const int* __restrict__ off1,
    float* __restrict__ out) {
    __shared__ float Bs[80 * 128];
    __shared__ float As[80 * AP];
    __shared__ float c2as[128], c2bs[128], f1s[128];
    int t = threadIdx.x;
    int nb0 = blockIdx.x << 7;
    for (int i = t; i < 2560; i += 256) {
        float4 v = *(const float4*)&Wcat[i << 2];
        *(float4*)&Bs[i << 2] = v;
    }
    if (t < 128) {
        c2as[t] = c2a[t];
        c2bs[t] = c2b[t];
        f1s[t] = fc1w[t];
    }
#pragma unroll
    for (int i = 0; i < 8; ++i) {
        int q = t + (i << 8);
        int node = q >> 4, kq = q & 15;
        float4 v = *(const float4*)&xb2[((nb0 + node) << 6) + (kq << 2)];
        As[(kq * 4 + 0) * AP + node] = v.x;
        As[(kq * 4 + 1) * AP + node] = v.y;
        As[(kq * 4 + 2) * AP + node] = v.z;
        As[(kq * 4 + 3) * AP + node] = v.w;
    }
#pragma unroll
    for (int i = 0; i < 2; ++i) {
        int q = t + (i << 8);
        int node = q >> 2, kq = q & 3;
        float4 v = *(const float4*)&xbar[((nb0 + node) << 4) + (kq << 2)];
        As[(64 + kq * 4 + 0) * AP + node] = v.x;
        As[(64 + kq * 4 + 1) * AP + node] = v.y;
        As[(64 + kq * 4 + 2) * AP + node] = v.z;
        As[(64 + kq * 4 + 3) * AP + node] = v.w;
    }
    __syncthreads();
    int tx = t & 15, ty = t >> 4;
    int u0 = tx << 3, n0 = ty << 3;
    float za[8][8];
#pragma unroll
    for (int i = 0; i < 8; ++i)
#pragma unroll
        for (int j = 0; j < 8; ++j) za[i][j] = 0.f;
#pragma unroll 4
    for (int k = 0; k < 80; ++k) {
        float4 alo = *(const float4*)&As[k * AP + n0];
        float4 ahi = *(const float4*)&As[k * AP + n0 + 4];
        float4 blo = *(const float4*)&Bs[(k << 7) + u0];
        float4 bhi = *(const float4*)&Bs[(k << 7) + u0 + 4];
        float aa[8] = {alo.x, alo.y, alo.z, alo.w, ahi.x, ahi.y, ahi.z, ahi.w};
        float bb[8] = {blo.x, blo.y, blo.z, blo.w, bhi.x, bhi.y, bhi.z, bhi.w};
#pragma unroll
        for (int i = 0; i < 8; ++i)
#pragma unroll
            for (int j = 0; j < 8; ++j) za[i][j] += aa[i] * bb[j];
    }
    float fb = fc1b[0];
#pragma unroll
    for (int i = 0; i < 8; ++i) {
        int bnn = nb0 + n0 + i;
        int nl = bnn & (NN - 1);
        int deg = off1[nl + 1] - off1[nl];
        float part = 0.f;
#pragma unroll
        for (int j = 0; j < 8; ++j) {
            int u = u0 + j;
            float z = za[i][j] + c2as[u] + (deg > 0 ? c2bs[u] : 0.f);
            z = z > 0.f ? z : 0.f;
            part += z * f1s[u];
        }
#pragma unroll
        for (int o = 8; o; o >>= 1) part += __shfl_xor(part, o);
        if (tx == 0) out[bnn] = part + fb;
    }
}

// ---------------- launch ----------------
extern "C" void kernel_launch(void* const* d_in, const int* in_sizes, int n_in,
                              void* d_out, int out_size, void* d_ws, size_t ws_size,
                              hipStream_t stream) {
    const float* x = (const float*)d_in[0];
    const int* ei0 = (const int*)d_in[2];
    const int* ei1 = (const int*)d_in[3];
    const float* W0 = (const float*)d_in[4];
    const float* atts0 = (const float*)d_in[5];
    const float* attd0 = (const float*)d_in[6];
    const float* b0 = (const float*)d_in[7];
    const float* W1 = (const float*)d_in[8];
    const float* atts1 = (const float*)d_in[9];
    const float* attd1 = (const float*)d_in[10];
    const float* b1 = (const float*)d_in[11];
    const float* fc0w = (const float*)d_in[12];
    const float* fc0b = (const float*)d_in[13];
    const float* fc1w = (const float*)d_in[14];
    const float* fc1b = (const float*)d_in[15];
    float* out = (float*)d_out;

    float* fw = (float*)d_ws;
    float* xbar = fw;                 fw += (size_t)BB * NN * 16;
    float* xb2 = fw;                  fw += (size_t)BB * NN * 64;
    float* as1 = fw;                  fw += (size_t)BB * NN * 4;
    float* ad1 = fw;                  fw += (size_t)BB * NN * 4;
    float* Ug = fw;                   fw += 4096;
    float* Wcat = fw;                 fw += 80 * 128;
    float* bbw1 = fw;                 fw += 256;
    float* c2a = fw;                  fw += 128;
    float* c2b = fw;                  fw += 128;
    float* ws0g = fw;                 fw += 16;
    float* wd0g = fw;                 fw += 16;
    float* Msg = fw;                  fw += 64;
    float* Mdg = fw;                  fw += 64;
    float* csg = fw;                  fw += 4;
    float* cdg = fw;                  fw += 4;
    float* ws1g = fw;                 fw += 1024;
    float* wd1g = fw;                 fw += 1024;
    int* ip = (int*)fw;
    int* off = ip;                    ip += 2 * (NN + 1);
    int* csr = ip;

    k_csr_prep1<<<9, 1024, 0, stream>>>(ei0, ei1, csr, off, W0, W1, atts0,
                                        attd0, atts1, attd1, ws1g, wd1g, ws0g,
                                        wd0g, Ug);
    k_prep2<<<1, 512, 0, stream>>>(W0, W1, b0, ws1g, wd1g, Msg, Mdg, csg, cdg,
                                   bbw1);
    k_agg0_prepB<<<2089, 256, 0, stream>>>(
        x, off, csr, ws0g, wd0g, Msg, Mdg, csg, cdg, xbar, as1, ad1, W0, fc0w,
        fc0b, b0, b1, bbw1, Ug, Wcat, c2a, c2b);
    k_agg1<<<BB * NN / 16, 256, 0, stream>>>(xbar, as1, ad1, off + (NN + 1),
                                             csr + EE, xb2);
    k_final<<<BB * NN / 128, 256, 0, stream>>>(xbar, xb2, Wcat, c2a, c2b, fc1w,
                                               fc1b, off + (NN + 1), out);
}

// Round 10
// 174.292 us; speedup vs baseline: 1.1345x; 1.0450x over previous
//
#include <hip/hip_runtime.h>

#define BB 32
#define NN 1024
#define EE 16384
#define NEG 0.2f

// ---------------- float4 helpers ----------------
__device__ __forceinline__ float4 f4(float v) { return make_float4(v, v, v, v); }
__device__ __forceinline__ float4 f4max(float4 a, float4 b) {
    return make_float4(fmaxf(a.x, b.x), fmaxf(a.y, b.y), fmaxf(a.z, b.z), fmaxf(a.w, b.w));
}
__device__ __forceinline__ float4 f4add(float4 a, float4 b) {
    return make_float4(a.x + b.x, a.y + b.y, a.z + b.z, a.w + b.w);
}
__device__ __forceinline__ float4 f4sub(float4 a, float4 b) {
    return make_float4(a.x - b.x, a.y - b.y, a.z - b.z, a.w - b.w);
}
__device__ __forceinline__ float4 f4mul(float4 a, float4 b) {
    return make_float4(a.x * b.x, a.y * b.y, a.z * b.z, a.w * b.w);
}
__device__ __forceinline__ float4 f4exp(float4 a) {
    return make_float4(__expf(a.x), __expf(a.y), __expf(a.z), __expf(a.w));
}
__device__ __forceinline__ float4 shflx4(float4 v, int o) {
    return make_float4(__shfl_xor(v.x, o), __shfl_xor(v.y, o),
                       __shfl_xor(v.z, o), __shfl_xor(v.w, o));
}
__device__ __forceinline__ float4 leaky4(float4 z) {
    return make_float4(z.x > 0.f ? z.x : NEG * z.x, z.y > 0.f ? z.y : NEG * z.y,
                       z.z > 0.f ? z.z : NEG * z.z, z.w > 0.f ? z.w : NEG * z.w);
}

// ======== D1: edge count (blocks 0..127, wide) + prep1 (128..152) ========
__global__ __launch_bounds__(256) void k_count_prep1(
    const int* __restrict__ ei0, const int* __restrict__ ei1,
    int* __restrict__ cnt, const float* __restrict__ W0,
    const float* __restrict__ W1, const float* __restrict__ atts0,
    const float* __restrict__ attd0, const float* __restrict__ atts1,
    const float* __restrict__ attd1, float* __restrict__ ws1g,
    float* __restrict__ wd1g, float* __restrict__ ws0g,
    float* __restrict__ wd0g, float* __restrict__ Ug) {
    int blk = blockIdx.x, t = threadIdx.x;
    if (blk < 128) {
        int list = blk >> 6;
        int e = ((blk & 63) << 8) + t;
        const int* ei = list ? ei1 : ei0;
        atomicAdd(&cnt[(list << 10) + ei[EE + e]], 1);
        return;
    }
    int gid = ((blk - 128) << 8) + t;
    if (gid < 4096) {
        int i = gid >> 8, tt = gid & 255;
        int hp = i >> 2, f = i & 3;
        float a = 0.f;
        for (int c = 0; c < 64; ++c)
            a += W0[f * 256 + hp * 64 + c] * W1[(hp * 64 + c) * 256 + tt];
        Ug[i * 256 + tt] = a;
    } else if (gid < 5120) {
        int q = gid - 4096;
        int tt = q >> 2, h = q & 3;
        float a = 0.f;
        for (int c = 0; c < 64; ++c)
            a += W1[tt * 256 + h * 64 + c] * atts1[h * 64 + c];
        ws1g[q] = a;
    } else if (gid < 6144) {
        int q = gid - 5120;
        int tt = q >> 2, h = q & 3;
        float a = 0.f;
        for (int c = 0; c < 64; ++c)
            a += W1[tt * 256 + h * 64 + c] * attd1[h * 64 + c];
        wd1g[q] = a;
    } else if (gid < 6176) {
        int q = gid - 6144;
        int sel = q >> 4, i = q & 15;
        int f = i >> 2, h = i & 3;
        const float* att = sel ? attd0 : atts0;
        float a = 0.f;
        for (int c = 0; c < 64; ++c)
            a += W0[f * 256 + h * 64 + c] * att[h * 64 + c];
        (sel ? wd0g : ws0g)[i] = a;
    }
}

// ======== D2: scan (blocks 0,1) + prep2 (blocks 2,3) ========
__global__ __launch_bounds__(1024) void k_scan_prep2(
    int* __restrict__ cnt, int* __restrict__ off,
    const float* __restrict__ W0, const float* __restrict__ W1,
    const float* __restrict__ b0, const float* __restrict__ ws1g,
    const float* __restrict__ wd1g, float* __restrict__ Msg,
    float* __restrict__ Mdg, float* __restrict__ csg, float* __restrict__ cdg,
    float* __restrict__ bbw1) {
    int blk = blockIdx.x, t = threadIdx.x;
    if (blk < 2) {
        __shared__ int s[NN];
        int* c = cnt + (blk << 10);
        int* o = off + blk * (NN + 1);
        int v0 = c[t];
        s[t] = v0;
        __syncthreads();
        for (int d = 1; d < NN; d <<= 1) {
            int v = (t >= d) ? s[t - d] : 0;
            __syncthreads();
            s[t] += v;
            __syncthreads();
        }
        int excl = s[t] - v0;
        o[t] = excl;
        c[t] = excl;   // becomes scatter cursor
        if (t == NN - 1) o[NN] = s[NN - 1];
        return;
    }
    if (blk == 2) {
        if (t < 64) {
            int i = t >> 2, h = t & 3;
            int hp = i >> 2, f = i & 3;
            float a = 0.f;
            for (int c = 0; c < 64; ++c)
                a += W0[f * 256 + hp * 64 + c] * ws1g[(hp * 64 + c) * 4 + h];
            Msg[t] = a;
        } else if (t < 128) {
            int q = t - 64;
            int i = q >> 2, h = q & 3;
            int hp = i >> 2, f = i & 3;
            float a = 0.f;
            for (int c = 0; c < 64; ++c)
                a += W0[f * 256 + hp * 64 + c] * wd1g[(hp * 64 + c) * 4 + h];
            Mdg[q] = a;
        } else if (t < 132) {
            int h = t - 128;
            float a = 0.f;
            for (int tt = 0; tt < 256; ++tt) a += b0[tt] * ws1g[tt * 4 + h];
            csg[h] = a;
        } else if (t < 136) {
            int h = t - 132;
            float a = 0.f;
            for (int tt = 0; tt < 256; ++tt) a += b0[tt] * wd1g[tt * 4 + h];
            cdg[h] = a;
        }
        return;
    }
    if (t < 256) {
        float a = 0.f;
        for (int tp = 0; tp < 256; ++tp) a += b0[tp] * W1[tp * 256 + t];
        bbw1[t] = a;
    }
}

// ======== D3: scatter (wide, 128 blocks) ========
__global__ __launch_bounds__(256) void k_scatter(
    const int* __restrict__ ei0, const int* __restrict__ ei1,
    int* __restrict__ cur, int* __restrict__ csr) {
    int list = blockIdx.x >> 6;
    int e = ((blockIdx.x & 63) << 8) + threadIdx.x;
    const int* ei = list ? ei1 : ei0;
    int sv = ei[e];
    int d = ei[EE + e];
    int p = atomicAdd(&cur[(list << 10) + d], 1);
    csr[(list << 14) + p] = sv;
}

// ======== D4: agg0 (blocks 0..2047, inline as0) + prepB (2048..2088) ========
__global__ __launch_bounds__(256) void k_agg0_prepB(
    const float* __restrict__ x, const int* __restrict__ off,
    const int* __restrict__ csr, const float* __restrict__ ws0g,
    const float* __restrict__ wd0g, const float* __restrict__ Msg,
    const float* __restrict__ Mdg, const float* __restrict__ csg,
    const float* __restrict__ cdg, float* __restrict__ xbar,
    float* __restrict__ as1, float* __restrict__ ad1,
    const float* __restrict__ W0, const float* __restrict__ fc0w,
    const float* __restrict__ fc0b, const float* __restrict__ b0,
    const float* __restrict__ b1, const float* __restrict__ bbw1,
    const float* __restrict__ Ug, float* __restrict__ Wcat,
    float* __restrict__ c2a, float* __restrict__ c2b) {
    int blk = blockIdx.x, t = threadIdx.x;
    if (blk >= 2048) {
        int gid = ((blk - 2048) << 8) + t;
        if (gid < 8192) {
            int row = gid >> 7, u = gid & 127;
            int h = row >> 4, j = row & 15;
            float a = 0.f;
            for (int c = 0; c < 64; ++c)
                a += Ug[j * 256 + h * 64 + c] * fc0w[(h * 64 + c) * 128 + u];
            Wcat[row * 128 + u] = a;
        } else if (gid < 10240) {
            int row = gid >> 7, u = gid & 127;
            int j = row - 64;
            int h = j >> 2, f = j & 3;
            float a = 0.f;
            for (int c = 0; c < 64; ++c)
                a += W0[f * 256 + h * 64 + c] * fc0w[(h * 64 + c) * 128 + u];
            Wcat[row * 128 + u] = a;
        } else if (gid < 10368) {
            int u = gid - 10240;
            float a = fc0b[u];
            for (int tt = 0; tt < 256; ++tt)
                a += (b1[tt] + b0[tt]) * fc0w[tt * 128 + u];
            c2a[u] = a;
        } else if (gid < 10496) {
            int u = gid - 10368;
            float a = 0.f;
            for (int tt = 0; tt < 256; ++tt) a += bbw1[tt] * fc0w[tt * 128 + u];
            c2b[u] = a;
        }
        return;
    }
    int g = t >> 4, l = t & 15;
    int bn = (blk << 4) + g;
    int b = bn >> 10, n = bn & (NN - 1);
    int beg = off[n], end = off[n + 1];
    float ws[16], wd[16];
#pragma unroll
    for (int i = 0; i < 16; ++i) {
        ws[i] = ws0g[i];
        wd[i] = wd0g[i];
    }
    float4 xd = *(const float4*)&x[bn << 2];
    float4 adv;
    adv.x = xd.x * wd[0] + xd.y * wd[4] + xd.z * wd[8] + xd.w * wd[12];
    adv.y = xd.x * wd[1] + xd.y * wd[5] + xd.z * wd[9] + xd.w * wd[13];
    adv.z = xd.x * wd[2] + xd.y * wd[6] + xd.z * wd[10] + xd.w * wd[14];
    adv.w = xd.x * wd[3] + xd.y * wd[7] + xd.z * wd[11] + xd.w * wd[15];
    float4 m4 = f4(-1e30f), den = f4(0.f);
    float pacc[16];
#pragma unroll
    for (int i = 0; i < 16; ++i) pacc[i] = 0.f;
    for (int base = beg + l; base < end; base += 16) {
        int s = csr[base];
        float4 xs = *(const float4*)&x[((b << 10) + s) << 2];
        float4 av;
        av.x = xs.x * ws[0] + xs.y * ws[4] + xs.z * ws[8] + xs.w * ws[12];
        av.y = xs.x * ws[1] + xs.y * ws[5] + xs.z * ws[9] + xs.w * ws[13];
        av.z = xs.x * ws[2] + xs.y * ws[6] + xs.z * ws[10] + xs.w * ws[14];
        av.w = xs.x * ws[3] + xs.y * ws[7] + xs.z * ws[11] + xs.w * ws[15];
        float4 lv = leaky4(f4add(av, adv));
        float4 nm = f4max(m4, lv);
        float4 r = f4exp(f4sub(m4, nm));
        float4 ex = f4exp(f4sub(lv, nm));
        m4 = nm;
        den = f4add(f4mul(den, r), ex);
        float rr[4] = {r.x, r.y, r.z, r.w};
        float exa[4] = {ex.x, ex.y, ex.z, ex.w};
        float xsa[4] = {xs.x, xs.y, xs.z, xs.w};
#pragma unroll
        for (int i = 0; i < 16; ++i)
            pacc[i] = pacc[i] * rr[i >> 2] + exa[i >> 2] * xsa[i & 3];
    }
    float4 ml = m4;
#pragma unroll
    for (int o = 8; o; o >>= 1) m4 = f4max(m4, shflx4(m4, o));
    float4 sc = f4exp(f4sub(ml, m4));
    den = f4mul(den, sc);
    float sca[4] = {sc.x, sc.y, sc.z, sc.w};
#pragma unroll
    for (int i = 0; i < 16; ++i) pacc[i] *= sca[i >> 2];
#pragma unroll
    for (int o = 8; o; o >>= 1) {
        den = f4add(den, shflx4(den, o));
#pragma unroll
        for (int i = 0; i < 16; ++i) pacc[i] += __shfl_xor(pacc[i], o);
    }
    float iva[4] = {1.f / (den.x + 1e-16f), 1.f / (den.y + 1e-16f),
                    1.f / (den.z + 1e-16f), 1.f / (den.w + 1e-16f)};
    float xbn[16];
#pragma unroll
    for (int i = 0; i < 16; ++i) xbn[i] = pacc[i] * iva[i >> 2];
    if (l == 0) {
#pragma unroll
        for (int q = 0; q < 4; ++q) {
            float4 v = make_float4(xbn[q * 4], xbn[q * 4 + 1], xbn[q * 4 + 2],
                                   xbn[q * 4 + 3]);
            *(float4*)&xbar[(bn << 4) + (q << 2)] = v;
        }
    }
    if (l < 8) {
        int h = l & 3, sel = l >> 2;
        const float* M = sel ? Mdg : Msg;
        float a = sel ? cdg[h] : csg[h];
#pragma unroll
        for (int i = 0; i < 16; ++i) a += xbn[i] * M[i * 4 + h];
        (sel ? ad1 : as1)[(bn << 2) + h] = a;
    }
}

// ======== D5: agg1 — 16-lane group per node, all 4 heads per lane ========
__global__ __launch_bounds__(256) void k_agg1(
    const float* __restrict__ xbar, const float* __restrict__ as1,
    const float* __restrict__ ad1, const int* __restrict__ off,
    const int* __restrict__ csr, float* __restrict__ xb2) {
    int t = threadIdx.x;
    int g = t >> 4, l = t & 15;
    int bn = (blockIdx.x << 4) + g;
    int b = bn >> 10, n = bn & (NN - 1);
    int beg = off[n], end = off[n + 1];
    float4 adv = *(const float4*)&ad1[bn << 2];
    float4 m4 = f4(-1e30f), den = f4(0.f);
    float pacc[64];
#pragma unroll
    for (int i = 0; i < 64; ++i) pacc[i] = 0.f;
    const float* xbb = xbar + ((size_t)b << 14);
    for (int base = beg + l; base < end; base += 16) {
        int s = csr[base];
        float4 av = *(const float4*)&as1[(((b << 10) + s)) << 2];
        float4 lv = leaky4(f4add(av, adv));
        float4 nm = f4max(m4, lv);
        float4 r = f4exp(f4sub(m4, nm));
        float4 ex = f4exp(f4sub(lv, nm));
        m4 = nm;
        den = f4add(f4mul(den, r), ex);
        const float* xp = xbb + (s << 4);
        float4 x0 = *(const float4*)(xp);
        float4 x1 = *(const float4*)(xp + 4);
        float4 x2 = *(const float4*)(xp + 8);
        float4 x3 = *(const float4*)(xp + 12);
        float rr[4] = {r.x, r.y, r.z, r.w};
        float exa[4] = {ex.x, ex.y, ex.z, ex.w};
        float xsa[16] = {x0.x, x0.y, x0.z, x0.w, x1.x, x1.y, x1.z, x1.w,
                         x2.x, x2.y, x2.z, x2.w, x3.x, x3.y, x3.z, x3.w};
#pragma unroll
        for (int h = 0; h < 4; ++h)
#pragma unroll
            for (int f = 0; f < 16; ++f)
                pacc[h * 16 + f] = pacc[h * 16 + f] * rr[h] + exa[h] * xsa[f];
    }
    float4 ml = m4;
#pragma unroll
    for (int o = 8; o; o >>= 1) m4 = f4max(m4, shflx4(m4, o));
    float4 sc = f4exp(f4sub(ml, m4));
    den = f4mul(den, sc);
    float sca[4] = {sc.x, sc.y, sc.z, sc.w};
#pragma unroll
    for (int i = 0; i < 64; ++i) pacc[i] *= sca[i >> 4];
#pragma unroll
    for (int o = 8; o; o >>= 1) {
        den = f4add(den, shflx4(den, o));
#pragma unroll
        for (int i = 0; i < 64; ++i) pacc[i] += __shfl_xor(pacc[i], o);
    }
    if (l == 0) {
        float iva[4] = {1.f / (den.x + 1e-16f), 1.f / (den.y + 1e-16f),
                        1.f / (den.z + 1e-16f), 1.f / (den.w + 1e-16f)};
#pragma unroll
        for (int q = 0; q < 16; ++q) {
            float iv = iva[q >> 2];
            float4 v = make_float4(pacc[q * 4] * iv, pacc[q * 4 + 1] * iv,
                                   pacc[q * 4 + 2] * iv, pacc[q * 4 + 3] * iv);
            *(float4*)&xb2[(bn << 6) + (q << 2)] = v;
        }
    }
}

// ======== D6: final GEMM + ReLU + 128-dot (128 nodes/block) ========
#define AP 132
__global__ __launch_bounds__(256) void k_final(
    const float* __restrict__ xbar, const float* __restrict__ xb2,
    const float* __restrict__ Wcat, const float* __restrict__ c2a,
    const float* __restrict__ c2b, const float* __restrict__ fc1w,
    const float* __restrict__ fc1b, const int* __restrict__ off1,
    float* __restrict__ out) {
    __shared__ float Bs[80 * 128];
    __shared__ float As[80 * AP];
    __shared__ float c2as[128], c2bs[128], f1s[128];
    int t = threadIdx.x;
    int nb0 = blockIdx.x << 7;
    for (int i = t; i < 2560; i += 256) {
        float4 v = *(const float4*)&Wcat[i << 2];
        *(float4*)&Bs[i << 2] = v;
    }
    if (t < 128) {
        c2as[t] = c2a[t];
        c2bs[t] = c2b[t];
        f1s[t] = fc1w[t];
    }
#pragma unroll
    for (int i = 0; i < 8; ++i) {
        int q = t + (i << 8);
        int node = q >> 4, kq = q & 15;
        float4 v = *(const float4*)&xb2[((nb0 + node) << 6) + (kq << 2)];
        As[(kq * 4 + 0) * AP + node] = v.x;
        As[(kq * 4 + 1) * AP + node] = v.y;
        As[(kq * 4 + 2) * AP + node] = v.z;
        As[(kq * 4 + 3) * AP + node] = v.w;
    }
#pragma unroll
    for (int i = 0; i < 2; ++i) {
        int q = t + (i << 8);
        int node = q >> 2, kq = q & 3;
        float4 v = *(const float4*)&xbar[((nb0 + node) << 4) + (kq << 2)];
        As[(64 + kq * 4 + 0) * AP + node] = v.x;
        As[(64 + kq * 4 + 1) * AP + node] = v.y;
        As[(64 + kq * 4 + 2) * AP + node] = v.z;
        As[(64 + kq * 4 + 3) * AP + node] = v.w;
    }
    __syncthreads();
    int tx = t & 15, ty = t >> 4;
    int u0 = tx << 3, n0 = ty << 3;
    float za[8][8];
#pragma unroll
    for (int i = 0; i < 8; ++i)
#pragma unroll
        for (int j = 0; j < 8; ++j) za[i][j] = 0.f;
#pragma unroll 4
    for (int k = 0; k < 80; ++k) {
        float4 alo = *(const float4*)&As[k * AP + n0];
        float4 ahi = *(const float4*)&As[k * AP + n0 + 4];
        float4 blo = *(const float4*)&Bs[(k << 7) + u0];
        float4 bhi = *(const float4*)&Bs[(k << 7) + u0 + 4];
        float aa[8] = {alo.x, alo.y, alo.z, alo.w, ahi.x, ahi.y, ahi.z, ahi.w};
        float bb[8] = {blo.x, blo.y, blo.z, blo.w, bhi.x, bhi.y, bhi.z, bhi.w};
#pragma unroll
        for (int i = 0; i < 8; ++i)
#pragma unroll
            for (int j = 0; j < 8; ++j) za[i][j] += aa[i] * bb[j];
    }
    float fb = fc1b[0];
#pragma unroll
    for (int i = 0; i < 8; ++i) {
        int bnn = nb0 + n0 + i;
        int nl = bnn & (NN - 1);
        int deg = off1[nl + 1] - off1[nl];
        float part = 0.f;
#pragma unroll
        for (int j = 0; j < 8; ++j) {
            int u = u0 + j;
            float z = za[i][j] + c2as[u] + (deg > 0 ? c2bs[u] : 0.f);
            z = z > 0.f ? z : 0.f;
            part += z * f1s[u];
        }
#pragma unroll
        for (int o = 8; o; o >>= 1) part += __shfl_xor(part, o);
        if (tx == 0) out[bnn] = part + fb;
    }
}

// ---------------- launch ----------------
extern "C" void kernel_launch(void* const* d_in, const int* in_sizes, int n_in,
                              void* d_out, int out_size, void* d_ws, size_t ws_size,
                              hipStream_t stream) {
    const float* x = (const float*)d_in[0];
    const int* ei0 = (const int*)d_in[2];
    const int* ei1 = (const int*)d_in[3];
    const float* W0 = (const float*)d_in[4];
    const float* atts0 = (const float*)d_in[5];
    const float* attd0 = (const float*)d_in[6];
    const float* b0 = (const float*)d_in[7];
    const float* W1 = (const float*)d_in[8];
    const float* atts1 = (const float*)d_in[9];
    const float* attd1 = (const float*)d_in[10];
    const float* b1 = (const float*)d_in[11];
    const float* fc0w = (const float*)d_in[12];
    const float* fc0b = (const float*)d_in[13];
    const float* fc1w = (const float*)d_in[14];
    const float* fc1b = (const float*)d_in[15];
    float* out = (float*)d_out;

    float* fw = (float*)d_ws;
    float* xbar = fw;                 fw += (size_t)BB * NN * 16;
    float* xb2 = fw;                  fw += (size_t)BB * NN * 64;
    float* as1 = fw;                  fw += (size_t)BB * NN * 4;
    float* ad1 = fw;                  fw += (size_t)BB * NN * 4;
    float* Ug = fw;                   fw += 4096;
    float* Wcat = fw;                 fw += 80 * 128;
    float* bbw1 = fw;                 fw += 256;
    float* c2a = fw;                  fw += 128;
    float* c2b = fw;                  fw += 128;
    float* ws0g = fw;                 fw += 16;
    float* wd0g = fw;                 fw += 16;
    float* Msg = fw;                  fw += 64;
    float* Mdg = fw;                  fw += 64;
    float* csg = fw;                  fw += 4;
    float* cdg = fw;                  fw += 4;
    float* ws1g = fw;                 fw += 1024;
    float* wd1g = fw;                 fw += 1024;
    int* ip = (int*)fw;
    int* off = ip;                    ip += 2 * (NN + 1);
    int* cnt = ip;                    ip += 2 * NN;
    int* csr = ip;

    hipMemsetAsync(cnt, 0, 2 * NN * sizeof(int), stream);
    k_count_prep1<<<153, 256, 0, stream>>>(ei0, ei1, cnt, W0, W1, atts0, attd0,
                                           atts1, attd1, ws1g, wd1g, ws0g,
                                           wd0g, Ug);
    k_scan_prep2<<<4, 1024, 0, stream>>>(cnt, off, W0, W1, b0, ws1g, wd1g,
                                         Msg, Mdg, csg, cdg, bbw1);
    k_scatter<<<128, 256, 0, stream>>>(ei0, ei1, cnt, csr);
    k_agg0_prepB<<<2089, 256, 0, stream>>>(
        x, off, csr, ws0g, wd0g, Msg, Mdg, csg, cdg, xbar, as1, ad1, W0, fc0w,
        fc0b, b0, b1, bbw1, Ug, Wcat, c2a, c2b);
    k_agg1<<<BB * NN / 16, 256, 0, stream>>>(xbar, as1, ad1, off + (NN + 1),
                                             csr + EE, xb2);
    k_final<<<BB * NN / 128, 256, 0, stream>>>(xbar, xb2, Wcat, c2a, c2b, fc1w,
                                               fc1b, off + (NN + 1), out);
}